// Round 11
// baseline (182.314 us; speedup 1.0000x reference)
//
#include <hip/hip_runtime.h>
#include <hip/hip_bf16.h>

// SelfAttention2D: B=4, C=256, H=W=64 (N=4096), Cqk=32.
// 3-kernel pipeline:
//  1) projx:   fused transpose+projection, 16-n tiles, grid 1024 (4+ blocks/CU).
//              x f32 -> 8KB swizzled LDS bf16 tile -> MFMA GEMM with inline-cvt W
//              -> V stored direct from acc; Q/K via small LDS stage (coalesced).
//              Q (weights+bias) pre-scaled 1/ln2.
//  2) attn:    flash attn, KV split 4-way; 4 waves x 32q, wave owns q end-to-end;
//              V+K staged via global_load_lds dbuf, swizzled; s_setprio on PV.
//  3) combine: out = gamma * (sum_k O_k) / (sum_k l_k) + x; grid 1024.

#define NB     4
#define CC     256
#define CQK    32
#define NPIX   4096
#define NCHUNK 4
#define CHUNK  (NPIX / NCHUNK)   // 1024
#define NT     (CHUNK / 64)      // 16 kv-tiles per chunk

typedef float floatx4 __attribute__((ext_vector_type(4)));
typedef short shortx4 __attribute__((ext_vector_type(4)));
typedef short shortx8 __attribute__((ext_vector_type(8)));

__device__ __forceinline__ short f2bf(float f) {
  unsigned u = __float_as_uint(f);
  u += 0x7fffu + ((u >> 16) & 1u);
  return (short)(u >> 16);
}
__device__ __forceinline__ float bf2f(unsigned short u) {
  return __uint_as_float((unsigned)u << 16);
}
__device__ __forceinline__ unsigned pk2bf(float a, float b) {
  union { __hip_bfloat162 h; unsigned u; } cv;
  cv.h = __float22bfloat162_rn(make_float2(a, b));  // v_cvt_pk_bf16_f32
  return cv.u;
}
__device__ __forceinline__ void gload16(const void* g, void* l) {
  __builtin_amdgcn_global_load_lds(
      (const __attribute__((address_space(1))) void*)g,
      (__attribute__((address_space(3))) void*)l, 16, 0, 0);
}

// ---------------------------------------------------------------------------
// 1) projx: grid 1024 = b(4) * nt(256 of 16 n); 256 threads / 4 waves.
//    Wave w owns o in [80w, 80w+80) (5 rowtiles of 16).
// ---------------------------------------------------------------------------
__global__ __launch_bounds__(256) void projx_kernel(
    const float* __restrict__ x,
    const float* __restrict__ wq, const float* __restrict__ bq,
    const float* __restrict__ wk, const float* __restrict__ bk,
    const float* __restrict__ wv, const float* __restrict__ bv,
    short* __restrict__ Qb, short* __restrict__ Kb, short* __restrict__ Vb)
{
  __shared__ short T[16 * 256];   // [n][c] bf16, swizzled within 64-c blocks
  __shared__ short SQK[16 * 72];  // [n][o<64] staging for coalesced Q/K stores

  const int gid = blockIdx.x;
  const int b = gid >> 8, n0 = (gid & 255) * 16;
  const int t = threadIdx.x, lane = t & 63, w = t >> 6;
  const int lo = lane & 15, hi = lane >> 4;

  // ---- phase A: x (C,16n) f32 -> T[n][c] bf16 (swizzled). 64B/row coalesced.
  {
    const int nq = (t & 3) * 4;
    const int cl = t >> 2;           // 0..63
#pragma unroll
    for (int rr = 0; rr < 4; rr++) {
      const int c = rr * 64 + cl;
      const floatx4 v = *(const floatx4*)(
          x + ((size_t)(b * CC + c)) * NPIX + n0 + nq);
#pragma unroll
      for (int i = 0; i < 4; i++) {
        const int n = nq + i;
        T[n * 256 + rr * 64 + (cl ^ ((n & 7) << 3))] = f2bf(v[i]);
      }
    }
  }
  __syncthreads();

  // ---- phase B: GEMM. A = W f32 inline-cvt; B from swizzled T.
  const float* wrow[5];
#pragma unroll
  for (int rt = 0; rt < 5; rt++) {
    const int o = w * 80 + rt * 16 + lo;   // 16-aligned ranges: no divergence
    wrow[rt] = (o < 32) ? (wq + (size_t)o * CC)
             : (o < 64) ? (wk + (size_t)(o - 32) * CC)
                        : (wv + (size_t)(o - 64) * CC);
  }

  floatx4 acc[5];
#pragma unroll
  for (int r = 0; r < 5; r++) acc[r] = (floatx4){0.f, 0.f, 0.f, 0.f};

#pragma unroll
  for (int c0 = 0; c0 < CC; c0 += 32) {
    const int c = c0 + hi * 8;
    const shortx8 bf = *(const shortx8*)
        &T[lo * 256 + (c & 192) + ((c & 63) ^ ((lo & 7) << 3))];
#pragma unroll
    for (int rt = 0; rt < 5; rt++) {
      const float* ap = wrow[rt] + c0 + hi * 8;
      floatx4 a0 = *(const floatx4*)ap;
      floatx4 a1 = *(const floatx4*)(ap + 4);
      if (w == 0 && rt < 2) {          // Q rows: fold 1/ln2 into A
        a0 *= 1.44269504088896f; a1 *= 1.44269504088896f;
      }
      union { shortx8 s; unsigned u[4]; } au;
      au.u[0] = pk2bf(a0[0], a0[1]);
      au.u[1] = pk2bf(a0[2], a0[3]);
      au.u[2] = pk2bf(a1[0], a1[1]);
      au.u[3] = pk2bf(a1[2], a1[3]);
      acc[rt] = __builtin_amdgcn_mfma_f32_16x16x32_bf16(au.s, bf, acc[rt], 0, 0, 0);
    }
  }
  __syncthreads();   // T dead; SQK writes follow

  // ---- epilogue: bias; V direct stores; Q/K -> SQK stage
#pragma unroll
  for (int rt = 0; rt < 5; rt++) {
#pragma unroll
    for (int j = 0; j < 4; j++) {
      const int o = w * 80 + rt * 16 + hi * 4 + j;
      const float bs = (o < 32) ? bq[o] * 1.44269504088896f
                     : (o < 64) ? bk[o - 32] : bv[o - 64];
      const short hv = f2bf(acc[rt][j] + bs);
      if (o < 64) SQK[lo * 72 + o] = hv;
      else        Vb[((size_t)(b * CC + (o - 64))) * NPIX + n0 + lo] = hv;
    }
  }
  __syncthreads();

  if (t < 128) {   // Q: t<64, K: 64<=t<128; contiguous 16B stores
    const int isK = t >> 6;
    const int flat = (t & 63) * 8;          // 0..504
    const int n = flat >> 5, o = flat & 31;
    const shortx8 d = *(const shortx8*)&SQK[n * 72 + isK * 32 + o];
    short* base = isK ? Kb : Qb;
    *(shortx8*)(base + ((size_t)(b * NPIX + n0 + n)) * CQK + o) = d;
  }
}

// ---------------------------------------------------------------------------
// 2) Flash attention (round-5 structure + s_setprio on PV). grid 512.
//    Block: 4 waves x 32 q = 128 q. LDS 80KB: V dbuf 64K + K dbuf 8K + P 8K.
// ---------------------------------------------------------------------------
__global__ __launch_bounds__(256, 2) void attn_kernel(
    const short* __restrict__ Qb, const short* __restrict__ Kb,
    const short* __restrict__ Vb,
    short* __restrict__ Opart, float* __restrict__ Lpart)
{
  __shared__ short Vl[2][16384];   // [c 256][kv 64], swz: elem ^= (c&7)<<3
  __shared__ short Kl[2][2048];    // [kv 64][d 32],  swz: elem ^= ((kv>>1)&3)<<3
  __shared__ short Pl[4][1024];    // per-wave [q 16][kv 64], swz: elem ^= (q&7)<<3

  const int bc = blockIdx.x & 15, qt = blockIdx.x >> 4;
  const int b = bc & 3, ch = bc >> 2;
  const int q0 = qt * 128, kv0 = ch * CHUNK;
  const int tid = threadIdx.x, lane = tid & 63, w = tid >> 6;
  const int lo = lane & 15, hi = lane >> 4;

  const short* Kc = Kb + ((size_t)(b * NPIX + kv0)) * CQK;
  const short* Vc = Vb + (size_t)b * CC * NPIX + kv0;

  shortx8 qf[2];
#pragma unroll
  for (int qs = 0; qs < 2; qs++)
    qf[qs] = *(const shortx8*)(
        Qb + ((size_t)(b * NPIX + q0 + w * 32 + qs * 16 + lo)) * CQK + hi * 8);

  const int cV = w * 64 + (lane >> 3);
  const int pcV = lane & 7;
  const int kvK = w * 16 + (lane >> 2);
  const int lcK = (lane & 3) ^ ((kvK >> 1) & 3);

  floatx4 oacc[2][16];
#pragma unroll
  for (int qs = 0; qs < 2; qs++)
#pragma unroll
    for (int i = 0; i < 16; i++) oacc[qs][i] = (floatx4){0.f, 0.f, 0.f, 0.f};
  float l[2] = {0.f, 0.f};
  const floatx4 zero4 = (floatx4){0.f, 0.f, 0.f, 0.f};

#pragma unroll
  for (int i = 0; i < 8; i++) {
    const int c = cV + i * 8;
    gload16(Vc + (size_t)c * NPIX + (pcV ^ (c & 7)) * 8, &Vl[0][w * 4096 + i * 512]);
  }
  gload16(Kc + (size_t)kvK * CQK + lcK * 8, &Kl[0][w * 512]);
  __syncthreads();

  for (int t = 0; t < NT; t++) {
    const int buf = t & 1;

    if (t + 1 < NT) {
      const int j0n = (t + 1) * 64;
#pragma unroll
      for (int i = 0; i < 8; i++) {
        const int c = cV + i * 8;
        gload16(Vc + (size_t)c * NPIX + j0n + (pcV ^ (c & 7)) * 8,
                &Vl[buf ^ 1][w * 4096 + i * 512]);
      }
      gload16(Kc + (size_t)(j0n + kvK) * CQK + lcK * 8, &Kl[buf ^ 1][w * 512]);
    }

    floatx4 s[2][4];
#pragma unroll
    for (int ct = 0; ct < 4; ct++) {
      const int kv = ct * 16 + lo;
      const shortx8 kf = *(const shortx8*)
          &Kl[buf][kv * 32 + ((hi * 8) ^ (((kv >> 1) & 3) << 3))];
      s[0][ct] = __builtin_amdgcn_mfma_f32_16x16x32_bf16(kf, qf[0], zero4, 0, 0, 0);
      s[1][ct] = __builtin_amdgcn_mfma_f32_16x16x32_bf16(kf, qf[1], zero4, 0, 0, 0);
    }

    shortx8 pb[2][2];
#pragma unroll
    for (int qs = 0; qs < 2; qs++) {
      float rs = 0.f;
#pragma unroll
      for (int ct = 0; ct < 4; ct++) {
        const float p0 = exp2f(s[qs][ct][0]), p1 = exp2f(s[qs][ct][1]);
        const float p2 = exp2f(s[qs][ct][2]), p3 = exp2f(s[qs][ct][3]);
        rs += (p0 + p1) + (p2 + p3);
        uint2 u;
        u.x = pk2bf(p0, p1);
        u.y = pk2bf(p2, p3);
        *(uint2*)&Pl[w][lo * 64 + ((ct * 16 + hi * 4) ^ ((lo & 7) << 3))] = u;
      }
#pragma unroll
      for (int h = 0; h < 2; h++)
        pb[qs][h] = *(const shortx8*)
            &Pl[w][lo * 64 + ((h * 32 + hi * 8) ^ ((lo & 7) << 3))];
      rs += __shfl_xor(rs, 16);
      rs += __shfl_xor(rs, 32);
      l[qs] += rs;
    }

    __builtin_amdgcn_s_setprio(1);
#pragma unroll
    for (int ctv = 0; ctv < 16; ctv++) {
      const int c = ctv * 16 + lo;
      const int swz = (c & 7) << 3;
      const shortx8 va0 = *(const shortx8*)&Vl[buf][c * 64 + ((hi * 8) ^ swz)];
      const shortx8 va1 = *(const shortx8*)&Vl[buf][c * 64 + ((32 + hi * 8) ^ swz)];
      oacc[0][ctv] = __builtin_amdgcn_mfma_f32_16x16x32_bf16(va0, pb[0][0], oacc[0][ctv], 0, 0, 0);
      oacc[0][ctv] = __builtin_amdgcn_mfma_f32_16x16x32_bf16(va1, pb[0][1], oacc[0][ctv], 0, 0, 0);
      oacc[1][ctv] = __builtin_amdgcn_mfma_f32_16x16x32_bf16(va0, pb[1][0], oacc[1][ctv], 0, 0, 0);
      oacc[1][ctv] = __builtin_amdgcn_mfma_f32_16x16x32_bf16(va1, pb[1][1], oacc[1][ctv], 0, 0, 0);
    }
    __builtin_amdgcn_s_setprio(0);

    __syncthreads();
  }

  if (hi == 0) {
    Lpart[(size_t)bc * NPIX + q0 + w * 32 + lo] = l[0];
    Lpart[(size_t)bc * NPIX + q0 + w * 32 + 16 + lo] = l[1];
  }
#pragma unroll
  for (int qs = 0; qs < 2; qs++) {
    const int n = q0 + w * 32 + qs * 16 + lo;
#pragma unroll
    for (int ctv = 0; ctv < 16; ctv++)
#pragma unroll
      for (int j = 0; j < 4; j++) {
        const int c = ctv * 16 + hi * 4 + j;
        Opart[((size_t)bc * CC + c) * NPIX + n] = f2bf(oacc[qs][ctv][j]);
      }
  }
}

// ---------------------------------------------------------------------------
// 3) Combine. grid 1024 = b(4) * cgrp(16 of 16c) * ngrp(16 of 256n).
// ---------------------------------------------------------------------------
__global__ __launch_bounds__(256) void combine_kernel(
    const short* __restrict__ Opart, const float* __restrict__ Lpart,
    const float* __restrict__ x, const float* __restrict__ gamma,
    float* __restrict__ out)
{
  __shared__ float linv[256];
  const int gid = blockIdx.x;
  const int b = gid >> 8;
  const int c0 = ((gid >> 4) & 15) * 16;
  const int n0 = (gid & 15) * 256;
  const int t = threadIdx.x;

  if (t < 64) {
    const int n = n0 + t * 4;
    floatx4 sum = (floatx4){0.f, 0.f, 0.f, 0.f};
#pragma unroll
    for (int k = 0; k < NCHUNK; k++)
      sum += *(const floatx4*)(Lpart + (size_t)(k * NB + b) * NPIX + n);
#pragma unroll
    for (int i = 0; i < 4; i++) linv[t * 4 + i] = 1.0f / sum[i];
  }
  __syncthreads();

  const float g = gamma[0];
  const int il = t & 31, cw = t >> 5;     // 32 n-slots x 8 c-slots
  const int n = n0 + il * 8;
  float li[8];
#pragma unroll
  for (int j = 0; j < 8; j++) li[j] = linv[il * 8 + j];

#pragma unroll
  for (int i = 0; i < 2; i++) {
    const int c = c0 + cw * 2 + i;
    float acc[8];
#pragma unroll
    for (int j = 0; j < 8; j++) acc[j] = 0.f;
#pragma unroll
    for (int k = 0; k < NCHUNK; k++) {
      const shortx8 o = *(const shortx8*)(
          Opart + ((size_t)((k * NB + b) * CC + c)) * NPIX + n);
#pragma unroll
      for (int j = 0; j < 8; j++) acc[j] += bf2f((unsigned short)o[j]);
    }
    const size_t idx = ((size_t)(b * CC + c)) * NPIX + n;
    const floatx4 x0 = *(const floatx4*)(x + idx);
    const floatx4 x1 = *(const floatx4*)(x + idx + 4);
    floatx4 r0, r1;
#pragma unroll
    for (int j = 0; j < 4; j++) {
      r0[j] = g * (acc[j] * li[j]) + x0[j];
      r1[j] = g * (acc[j + 4] * li[j + 4]) + x1[j];
    }
    *(floatx4*)(out + idx) = r0;
    *(floatx4*)(out + idx + 4) = r1;
  }
}

extern "C" void kernel_launch(void* const* d_in, const int* in_sizes, int n_in,
                              void* d_out, int out_size, void* d_ws, size_t ws_size,
                              hipStream_t stream) {
  const float* x     = (const float*)d_in[0];
  const float* wq    = (const float*)d_in[1];
  const float* bq    = (const float*)d_in[2];
  const float* wk    = (const float*)d_in[3];
  const float* bk    = (const float*)d_in[4];
  const float* wv    = (const float*)d_in[5];
  const float* bv    = (const float*)d_in[6];
  const float* gamma = (const float*)d_in[7];
  float* out = (float*)d_out;

  char* p = (char*)d_ws;
  short* Qb    = (short*)p; p += (size_t)NB * NPIX * CQK * 2;            // 1 MB
  short* Kb    = (short*)p; p += (size_t)NB * NPIX * CQK * 2;            // 1 MB
  short* Vb    = (short*)p; p += (size_t)NB * CC * NPIX * 2;             // 8 MB
  short* Opart = (short*)p; p += (size_t)(NCHUNK * NB) * CC * NPIX * 2;  // 32 MB
  float* Lpart = (float*)p; p += (size_t)(NCHUNK * NB) * NPIX * 4;       // 256 KB

  projx_kernel<<<dim3(1024), dim3(256), 0, stream>>>(x, wq, bq, wk, bk, wv, bv, Qb, Kb, Vb);
  attn_kernel<<<dim3(512), dim3(256), 0, stream>>>(Qb, Kb, Vb, Opart, Lpart);
  combine_kernel<<<dim3(1024), dim3(256), 0, stream>>>(Opart, Lpart, x, gamma, out);
}

// Round 12
// 161.959 us; speedup vs baseline: 1.1257x; 1.1257x over previous
//
#include <hip/hip_runtime.h>
#include <hip/hip_bf16.h>

// SelfAttention2D: B=4, C=256, H=W=64 (N=4096), Cqk=32.
// 4-kernel pipeline:
//  1) prep:    W(q|k|v) f32 -> Wall[320][256] bf16, Q rows pre-scaled 1/ln2.
//  2) projx:   transpose+projection GEMM. grid 512 = b(4) x nt(128 of 32 n),
//              512 threads / 8 waves (4 waves/SIMD). x -> 16KB swizzled LDS
//              bf16 tile; A-frags straight 16B loads from Wall (L2-hot);
//              V direct stores; Q/K via LDS stage (coalesced 16B).
//  3) attn:    flash attn, KV split 4-way (round-6 proven version, NO setprio).
//  4) combine: out = gamma * (sum_k O_k) / (sum_k l_k) + x; grid 1024.

#define NB     4
#define CC     256
#define CQK    32
#define NPIX   4096
#define NCHUNK 4
#define CHUNK  (NPIX / NCHUNK)   // 1024
#define NT     (CHUNK / 64)      // 16 kv-tiles per chunk

typedef float floatx4 __attribute__((ext_vector_type(4)));
typedef short shortx4 __attribute__((ext_vector_type(4)));
typedef short shortx8 __attribute__((ext_vector_type(8)));

__device__ __forceinline__ short f2bf(float f) {
  unsigned u = __float_as_uint(f);
  u += 0x7fffu + ((u >> 16) & 1u);
  return (short)(u >> 16);
}
__device__ __forceinline__ float bf2f(unsigned short u) {
  return __uint_as_float((unsigned)u << 16);
}
__device__ __forceinline__ unsigned pk2bf(float a, float b) {
  union { __hip_bfloat162 h; unsigned u; } cv;
  cv.h = __float22bfloat162_rn(make_float2(a, b));  // v_cvt_pk_bf16_f32
  return cv.u;
}
__device__ __forceinline__ void gload16(const void* g, void* l) {
  __builtin_amdgcn_global_load_lds(
      (const __attribute__((address_space(1))) void*)g,
      (__attribute__((address_space(3))) void*)l, 16, 0, 0);
}

// ---------------------------------------------------------------------------
// 1) Weights -> bf16, packed [320][256]; Q rows (o<32) pre-scaled by 1/ln2.
// ---------------------------------------------------------------------------
__global__ __launch_bounds__(256) void prep_kernel(
    const float* __restrict__ wq, const float* __restrict__ wk,
    const float* __restrict__ wv, short* __restrict__ Wall)
{
  const int e = (blockIdx.x * 256 + threadIdx.x) * 4;  // 80 blocks exact
  const int o = e >> 8, c = e & 255;
  const float* src = (o < 32) ? (wq + (size_t)o * CC + c)
                   : (o < 64) ? (wk + (size_t)(o - 32) * CC + c)
                              : (wv + (size_t)(o - 64) * CC + c);
  const float scale = (o < 32) ? 1.44269504088896f : 1.0f;
  const floatx4 v = *(const floatx4*)src;
  shortx4 r;
#pragma unroll
  for (int i = 0; i < 4; i++) r[i] = f2bf(v[i] * scale);
  *(shortx4*)(Wall + e) = r;
}

// ---------------------------------------------------------------------------
// 2) projx: grid 512 = b(4) * nt(128 of 32 n); 512 threads / 8 waves.
//    Wave w: wn = w&1 (16-n half), wo = w>>1 (80-o quarter, 5 rowtiles).
// ---------------------------------------------------------------------------
__global__ __launch_bounds__(512) void projx_kernel(
    const float* __restrict__ x, const short* __restrict__ Wall,
    const float* __restrict__ bq, const float* __restrict__ bk,
    const float* __restrict__ bv,
    short* __restrict__ Qb, short* __restrict__ Kb, short* __restrict__ Vb)
{
  __shared__ short T[32 * 256];   // [n][c] bf16, swizzled within 64-c blocks
  __shared__ short SQK[32 * 72];  // [n][o<64] staging for coalesced Q/K stores

  const int gid = blockIdx.x;
  const int b = gid >> 7, n0 = (gid & 127) * 32;
  const int t = threadIdx.x, lane = t & 63, w = t >> 6;
  const int lo = lane & 15, hi = lane >> 4;

  // ---- phase A: x (C, 32 n) f32 -> T[n][c] bf16 (swizzled). 128B/row.
  {
    const int cl = t >> 3;          // 0..63
    const int ln = t & 7;           // 8 lanes x 16B = 128B per c-row
#pragma unroll
    for (int p = 0; p < 4; p++) {
      const int c = p * 64 + cl;
      const floatx4 v = *(const floatx4*)(
          x + ((size_t)(b * CC + c)) * NPIX + n0 + ln * 4);
#pragma unroll
      for (int i = 0; i < 4; i++) {
        const int n = ln * 4 + i;
        T[n * 256 + (c & 192) + ((c & 63) ^ ((n & 7) << 3))] = f2bf(v[i]);
      }
    }
  }
  __syncthreads();

  // ---- phase B: GEMM. A = Wall bf16 16B loads; B from swizzled T.
  const int wn = w & 1, wo = w >> 1;
  const int nn = wn * 16 + lo;
  const short* arow = Wall + (size_t)(wo * 80 + lo) * CC + hi * 8;

  floatx4 acc[5];
#pragma unroll
  for (int r = 0; r < 5; r++) acc[r] = (floatx4){0.f, 0.f, 0.f, 0.f};

#pragma unroll
  for (int c0 = 0; c0 < CC; c0 += 32) {
    const int c = c0 + hi * 8;
    const shortx8 bf = *(const shortx8*)
        &T[nn * 256 + (c & 192) + ((c & 63) ^ ((nn & 7) << 3))];
#pragma unroll
    for (int rt = 0; rt < 5; rt++) {
      const shortx8 a = *(const shortx8*)(arow + (size_t)rt * 16 * CC + c0);
      acc[rt] = __builtin_amdgcn_mfma_f32_16x16x32_bf16(a, bf, acc[rt], 0, 0, 0);
    }
  }

  // ---- epilogue: bias; V direct stores; Q/K -> SQK stage
#pragma unroll
  for (int rt = 0; rt < 5; rt++) {
#pragma unroll
    for (int j = 0; j < 4; j++) {
      const int o = wo * 80 + rt * 16 + hi * 4 + j;   // class uniform per rt
      const float bs = (o < 32) ? bq[o] * 1.44269504088896f
                     : (o < 64) ? bk[o - 32] : bv[o - 64];
      const short hv = f2bf(acc[rt][j] + bs);
      if (o < 64) SQK[nn * 72 + o] = hv;
      else        Vb[((size_t)(b * CC + (o - 64))) * NPIX + n0 + nn] = hv;
    }
  }
  __syncthreads();

  if (t < 256) {   // Q: t<128, K: 128<=t<256; 4x16B = 64B contiguous per row
    const int isK = t >> 7;
    const int r = t & 127;
    const int n = r >> 2, oseg = (r & 3) * 8;
    const shortx8 d = *(const shortx8*)&SQK[n * 72 + isK * 32 + oseg];
    short* base = isK ? Kb : Qb;
    *(shortx8*)(base + ((size_t)(b * NPIX + n0 + n)) * CQK + oseg) = d;
  }
}

// ---------------------------------------------------------------------------
// 3) Flash attention (round-6 proven version, no setprio). grid 512.
//    Block: 4 waves x 32 q = 128 q. LDS 80KB: V dbuf 64K + K dbuf 8K + P 8K.
// ---------------------------------------------------------------------------
__global__ __launch_bounds__(256, 2) void attn_kernel(
    const short* __restrict__ Qb, const short* __restrict__ Kb,
    const short* __restrict__ Vb,
    short* __restrict__ Opart, float* __restrict__ Lpart)
{
  __shared__ short Vl[2][16384];   // [c 256][kv 64], swz: elem ^= (c&7)<<3
  __shared__ short Kl[2][2048];    // [kv 64][d 32],  swz: elem ^= ((kv>>1)&3)<<3
  __shared__ short Pl[4][1024];    // per-wave [q 16][kv 64], swz: elem ^= (q&7)<<3

  const int bc = blockIdx.x & 15, qt = blockIdx.x >> 4;
  const int b = bc & 3, ch = bc >> 2;
  const int q0 = qt * 128, kv0 = ch * CHUNK;
  const int tid = threadIdx.x, lane = tid & 63, w = tid >> 6;
  const int lo = lane & 15, hi = lane >> 4;

  const short* Kc = Kb + ((size_t)(b * NPIX + kv0)) * CQK;
  const short* Vc = Vb + (size_t)b * CC * NPIX + kv0;

  shortx8 qf[2];
#pragma unroll
  for (int qs = 0; qs < 2; qs++)
    qf[qs] = *(const shortx8*)(
        Qb + ((size_t)(b * NPIX + q0 + w * 32 + qs * 16 + lo)) * CQK + hi * 8);

  const int cV = w * 64 + (lane >> 3);
  const int pcV = lane & 7;
  const int kvK = w * 16 + (lane >> 2);
  const int lcK = (lane & 3) ^ ((kvK >> 1) & 3);

  floatx4 oacc[2][16];
#pragma unroll
  for (int qs = 0; qs < 2; qs++)
#pragma unroll
    for (int i = 0; i < 16; i++) oacc[qs][i] = (floatx4){0.f, 0.f, 0.f, 0.f};
  float l[2] = {0.f, 0.f};
  const floatx4 zero4 = (floatx4){0.f, 0.f, 0.f, 0.f};

#pragma unroll
  for (int i = 0; i < 8; i++) {
    const int c = cV + i * 8;
    gload16(Vc + (size_t)c * NPIX + (pcV ^ (c & 7)) * 8, &Vl[0][w * 4096 + i * 512]);
  }
  gload16(Kc + (size_t)kvK * CQK + lcK * 8, &Kl[0][w * 512]);
  __syncthreads();

  for (int t = 0; t < NT; t++) {
    const int buf = t & 1;

    if (t + 1 < NT) {
      const int j0n = (t + 1) * 64;
#pragma unroll
      for (int i = 0; i < 8; i++) {
        const int c = cV + i * 8;
        gload16(Vc + (size_t)c * NPIX + j0n + (pcV ^ (c & 7)) * 8,
                &Vl[buf ^ 1][w * 4096 + i * 512]);
      }
      gload16(Kc + (size_t)(j0n + kvK) * CQK + lcK * 8, &Kl[buf ^ 1][w * 512]);
    }

    floatx4 s[2][4];
#pragma unroll
    for (int ct = 0; ct < 4; ct++) {
      const int kv = ct * 16 + lo;
      const shortx8 kf = *(const shortx8*)
          &Kl[buf][kv * 32 + ((hi * 8) ^ (((kv >> 1) & 3) << 3))];
      s[0][ct] = __builtin_amdgcn_mfma_f32_16x16x32_bf16(kf, qf[0], zero4, 0, 0, 0);
      s[1][ct] = __builtin_amdgcn_mfma_f32_16x16x32_bf16(kf, qf[1], zero4, 0, 0, 0);
    }

    shortx8 pb[2][2];
#pragma unroll
    for (int qs = 0; qs < 2; qs++) {
      float rs = 0.f;
#pragma unroll
      for (int ct = 0; ct < 4; ct++) {
        const float p0 = exp2f(s[qs][ct][0]), p1 = exp2f(s[qs][ct][1]);
        const float p2 = exp2f(s[qs][ct][2]), p3 = exp2f(s[qs][ct][3]);
        rs += (p0 + p1) + (p2 + p3);
        uint2 u;
        u.x = pk2bf(p0, p1);
        u.y = pk2bf(p2, p3);
        *(uint2*)&Pl[w][lo * 64 + ((ct * 16 + hi * 4) ^ ((lo & 7) << 3))] = u;
      }
#pragma unroll
      for (int h = 0; h < 2; h++)
        pb[qs][h] = *(const shortx8*)
            &Pl[w][lo * 64 + ((h * 32 + hi * 8) ^ ((lo & 7) << 3))];
      rs += __shfl_xor(rs, 16);
      rs += __shfl_xor(rs, 32);
      l[qs] += rs;
    }

#pragma unroll
    for (int ctv = 0; ctv < 16; ctv++) {
      const int c = ctv * 16 + lo;
      const int swz = (c & 7) << 3;
      const shortx8 va0 = *(const shortx8*)&Vl[buf][c * 64 + ((hi * 8) ^ swz)];
      const shortx8 va1 = *(const shortx8*)&Vl[buf][c * 64 + ((32 + hi * 8) ^ swz)];
      oacc[0][ctv] = __builtin_amdgcn_mfma_f32_16x16x32_bf16(va0, pb[0][0], oacc[0][ctv], 0, 0, 0);
      oacc[0][ctv] = __builtin_amdgcn_mfma_f32_16x16x32_bf16(va1, pb[0][1], oacc[0][ctv], 0, 0, 0);
      oacc[1][ctv] = __builtin_amdgcn_mfma_f32_16x16x32_bf16(va0, pb[1][0], oacc[1][ctv], 0, 0, 0);
      oacc[1][ctv] = __builtin_amdgcn_mfma_f32_16x16x32_bf16(va1, pb[1][1], oacc[1][ctv], 0, 0, 0);
    }

    __syncthreads();
  }

  if (hi == 0) {
    Lpart[(size_t)bc * NPIX + q0 + w * 32 + lo] = l[0];
    Lpart[(size_t)bc * NPIX + q0 + w * 32 + 16 + lo] = l[1];
  }
#pragma unroll
  for (int qs = 0; qs < 2; qs++) {
    const int n = q0 + w * 32 + qs * 16 + lo;
#pragma unroll
    for (int ctv = 0; ctv < 16; ctv++)
#pragma unroll
      for (int j = 0; j < 4; j++) {
        const int c = ctv * 16 + hi * 4 + j;
        Opart[((size_t)bc * CC + c) * NPIX + n] = f2bf(oacc[qs][ctv][j]);
      }
  }
}

// ---------------------------------------------------------------------------
// 4) Combine. grid 1024 = b(4) * cgrp(16 of 16c) * ngrp(16 of 256n).
// ---------------------------------------------------------------------------
__global__ __launch_bounds__(256) void combine_kernel(
    const short* __restrict__ Opart, const float* __restrict__ Lpart,
    const float* __restrict__ x, const float* __restrict__ gamma,
    float* __restrict__ out)
{
  __shared__ float linv[256];
  const int gid = blockIdx.x;
  const int b = gid >> 8;
  const int c0 = ((gid >> 4) & 15) * 16;
  const int n0 = (gid & 15) * 256;
  const int t = threadIdx.x;

  if (t < 64) {
    const int n = n0 + t * 4;
    floatx4 sum = (floatx4){0.f, 0.f, 0.f, 0.f};
#pragma unroll
    for (int k = 0; k < NCHUNK; k++)
      sum += *(const floatx4*)(Lpart + (size_t)(k * NB + b) * NPIX + n);
#pragma unroll
    for (int i = 0; i < 4; i++) linv[t * 4 + i] = 1.0f / sum[i];
  }
  __syncthreads();

  const float g = gamma[0];
  const int il = t & 31, cw = t >> 5;     // 32 n-slots x 8 c-slots
  const int n = n0 + il * 8;
  float li[8];
#pragma unroll
  for (int j = 0; j < 8; j++) li[j] = linv[il * 8 + j];

#pragma unroll
  for (int i = 0; i < 2; i++) {
    const int c = c0 + cw * 2 + i;
    float acc[8];
#pragma unroll
    for (int j = 0; j < 8; j++) acc[j] = 0.f;
#pragma unroll
    for (int k = 0; k < NCHUNK; k++) {
      const shortx8 o = *(const shortx8*)(
          Opart + ((size_t)((k * NB + b) * CC + c)) * NPIX + n);
#pragma unroll
      for (int j = 0; j < 8; j++) acc[j] += bf2f((unsigned short)o[j]);
    }
    const size_t idx = ((size_t)(b * CC + c)) * NPIX + n;
    const floatx4 x0 = *(const floatx4*)(x + idx);
    const floatx4 x1 = *(const floatx4*)(x + idx + 4);
    floatx4 r0, r1;
#pragma unroll
    for (int j = 0; j < 4; j++) {
      r0[j] = g * (acc[j] * li[j]) + x0[j];
      r1[j] = g * (acc[j + 4] * li[j + 4]) + x1[j];
    }
    *(floatx4*)(out + idx) = r0;
    *(floatx4*)(out + idx + 4) = r1;
  }
}

extern "C" void kernel_launch(void* const* d_in, const int* in_sizes, int n_in,
                              void* d_out, int out_size, void* d_ws, size_t ws_size,
                              hipStream_t stream) {
  const float* x     = (const float*)d_in[0];
  const float* wq    = (const float*)d_in[1];
  const float* bq    = (const float*)d_in[2];
  const float* wk    = (const float*)d_in[3];
  const float* bk    = (const float*)d_in[4];
  const float* wv    = (const float*)d_in[5];
  const float* bv    = (const float*)d_in[6];
  const float* gamma = (const float*)d_in[7];
  float* out = (float*)d_out;

  char* p = (char*)d_ws;
  short* Wall  = (short*)p; p += (size_t)320 * CC * 2;                   // 160 KB
  short* Qb    = (short*)p; p += (size_t)NB * NPIX * CQK * 2;            // 1 MB
  short* Kb    = (short*)p; p += (size_t)NB * NPIX * CQK * 2;            // 1 MB
  short* Vb    = (short*)p; p += (size_t)NB * CC * NPIX * 2;             // 8 MB
  short* Opart = (short*)p; p += (size_t)(NCHUNK * NB) * CC * NPIX * 2;  // 32 MB
  float* Lpart = (float*)p; p += (size_t)(NCHUNK * NB) * NPIX * 4;       // 256 KB

  prep_kernel<<<dim3(80), dim3(256), 0, stream>>>(wq, wk, wv, Wall);
  projx_kernel<<<dim3(512), dim3(512), 0, stream>>>(x, Wall, bq, bk, bv, Qb, Kb, Vb);
  attn_kernel<<<dim3(512), dim3(256), 0, stream>>>(Qb, Kb, Vb, Opart, Lpart);
  combine_kernel<<<dim3(1024), dim3(256), 0, stream>>>(Opart, Lpart, x, gamma, out);
}